// Round 3
// baseline (596.694 us; speedup 1.0000x reference)
//
#include <hip/hip_runtime.h>

// TripleBatchTransform: roll(move) -> +noise*0.04 -> pairwise mean-pool
// (written twice) -> per-row standardize.
//
// p[j] = 0.5*(x[(2j-mv)%L] + x[(2j+1-mv)%L]) + 0.02*(noise[2j]+noise[2j+1])
// out[2j] = out[2j+1] = (p[j]-mu)*rsqrt(var), stats over pooled values
// (repeat-twice preserves mean/std).
//
// R3: R2 latency fix (8 pooled/thread/iter, 4x float4 x-loads + 4x float4
// noise-loads = 64B/lane in flight) with the nontemporal-store compile fix:
// use clang ext_vector_type(4) float (native vector) instead of HIP's
// float4 class for __builtin_nontemporal_store.

#define THREADS 1024
#define NWAVES (THREADS / 64)
#define V 8  // pooled values per thread per group

typedef float vf4 __attribute__((ext_vector_type(4)));

__global__ __launch_bounds__(THREADS) void tbt_kernel(
    const float* __restrict__ x,
    const float* __restrict__ noise,
    const int* __restrict__ movep,
    float* __restrict__ out,
    int L)
{
    const int b   = blockIdx.x;
    const int tid = threadIdx.x;
    const int J   = L >> 1;        // pooled count per row
    const int G   = J / V;         // full groups of V pooled values

    int mv = movep[0];
    mv %= L;
    if (mv < 0) mv += L;

    const float* __restrict__ xrow = x + (size_t)b * (size_t)L;
    float* __restrict__ orow       = out + (size_t)b * (size_t)L;

    // 16B-aligned fast path needs (16g - mv) % 4 == 0 -> mv % 4 == 0.
    const bool fast = ((mv & 3) == 0) && ((L & 1) == 0);

    float sum = 0.f, sumsq = 0.f;
    float p[V];

    if (fast) {
        for (int g = tid; g < G; g += THREADS) {
            const int s0 = 2 * V * g - mv;
            if (s0 >= 0 && s0 + 2 * V <= L) {
                const vf4* xp = (const vf4*)(xrow + s0);
                const vf4* np = (const vf4*)(noise + 2 * V * g);
                vf4 xa = xp[0], xb = xp[1], xc = xp[2], xd = xp[3];
                vf4 na = np[0], nb = np[1], nc = np[2], nd = np[3];
                p[0] = 0.5f * (xa.x + xa.y) + 0.02f * (na.x + na.y);
                p[1] = 0.5f * (xa.z + xa.w) + 0.02f * (na.z + na.w);
                p[2] = 0.5f * (xb.x + xb.y) + 0.02f * (nb.x + nb.y);
                p[3] = 0.5f * (xb.z + xb.w) + 0.02f * (nb.z + nb.w);
                p[4] = 0.5f * (xc.x + xc.y) + 0.02f * (nc.x + nc.y);
                p[5] = 0.5f * (xc.z + xc.w) + 0.02f * (nc.z + nc.w);
                p[6] = 0.5f * (xd.x + xd.y) + 0.02f * (nd.x + nd.y);
                p[7] = 0.5f * (xd.z + xd.w) + 0.02f * (nd.z + nd.w);
            } else {
                #pragma unroll
                for (int k = 0; k < V; ++k) {
                    int j = V * g + k;
                    int s = 2 * j - mv; if (s < 0) s += L;
                    int s1 = s + 1;     if (s1 >= L) s1 -= L;
                    p[k] = 0.5f * (xrow[s] + xrow[s1])
                         + 0.02f * (noise[2 * j] + noise[2 * j + 1]);
                }
            }
            #pragma unroll
            for (int k = 0; k < V; ++k) { sum += p[k]; sumsq += p[k] * p[k]; }
        }
        // tail (J % V != 0)
        for (int j = G * V + tid; j < J; j += THREADS) {
            int s = 2 * j - mv; if (s < 0) s += L;
            int s1 = s + 1;     if (s1 >= L) s1 -= L;
            float pv = 0.5f * (xrow[s] + xrow[s1])
                     + 0.02f * (noise[2 * j] + noise[2 * j + 1]);
            sum += pv; sumsq += pv * pv;
        }
    } else {
        for (int j = tid; j < J; j += THREADS) {
            int s = 2 * j - mv; if (s < 0) s += L;
            int s1 = s + 1;     if (s1 >= L) s1 -= L;
            float pv = 0.5f * (xrow[s] + xrow[s1])
                     + 0.02f * (noise[2 * j] + noise[2 * j + 1]);
            sum += pv; sumsq += pv * pv;
        }
    }

    // wave reduction (64 lanes)
    #pragma unroll
    for (int off = 32; off > 0; off >>= 1) {
        sum   += __shfl_down(sum,   off, 64);
        sumsq += __shfl_down(sumsq, off, 64);
    }

    __shared__ float s_sum[NWAVES], s_sq[NWAVES];
    __shared__ float s_mu, s_isd;
    const int wave = tid >> 6;
    const int lane = tid & 63;
    if (lane == 0) { s_sum[wave] = sum; s_sq[wave] = sumsq; }
    __syncthreads();
    if (tid == 0) {
        float ts = 0.f, tq = 0.f;
        #pragma unroll
        for (int w = 0; w < NWAVES; ++w) { ts += s_sum[w]; tq += s_sq[w]; }
        float invJ = 1.0f / (float)J;
        float mu   = ts * invJ;
        float var  = tq * invJ - mu * mu;
        s_mu  = mu;
        s_isd = rsqrtf(fmaxf(var, 1e-30f));
    }
    __syncthreads();
    const float mu  = s_mu;
    const float isd = s_isd;

    // pass 2: recompute pooled (x re-read hits L3), write both slots,
    // nontemporal stores (output never re-read; don't evict x from L3)
    if (fast) {
        for (int g = tid; g < G; g += THREADS) {
            const int s0 = 2 * V * g - mv;
            if (s0 >= 0 && s0 + 2 * V <= L) {
                const vf4* xp = (const vf4*)(xrow + s0);
                const vf4* np = (const vf4*)(noise + 2 * V * g);
                vf4 xa = xp[0], xb = xp[1], xc = xp[2], xd = xp[3];
                vf4 na = np[0], nb = np[1], nc = np[2], nd = np[3];
                p[0] = 0.5f * (xa.x + xa.y) + 0.02f * (na.x + na.y);
                p[1] = 0.5f * (xa.z + xa.w) + 0.02f * (na.z + na.w);
                p[2] = 0.5f * (xb.x + xb.y) + 0.02f * (nb.x + nb.y);
                p[3] = 0.5f * (xb.z + xb.w) + 0.02f * (nb.z + nb.w);
                p[4] = 0.5f * (xc.x + xc.y) + 0.02f * (nc.x + nc.y);
                p[5] = 0.5f * (xc.z + xc.w) + 0.02f * (nc.z + nc.w);
                p[6] = 0.5f * (xd.x + xd.y) + 0.02f * (nd.x + nd.y);
                p[7] = 0.5f * (xd.z + xd.w) + 0.02f * (nd.z + nd.w);
            } else {
                #pragma unroll
                for (int k = 0; k < V; ++k) {
                    int j = V * g + k;
                    int s = 2 * j - mv; if (s < 0) s += L;
                    int s1 = s + 1;     if (s1 >= L) s1 -= L;
                    p[k] = 0.5f * (xrow[s] + xrow[s1])
                         + 0.02f * (noise[2 * j] + noise[2 * j + 1]);
                }
            }
            vf4* op = (vf4*)(orow + 2 * V * g);
            vf4 r01 = { (p[0]-mu)*isd, (p[0]-mu)*isd, (p[1]-mu)*isd, (p[1]-mu)*isd };
            vf4 r23 = { (p[2]-mu)*isd, (p[2]-mu)*isd, (p[3]-mu)*isd, (p[3]-mu)*isd };
            vf4 r45 = { (p[4]-mu)*isd, (p[4]-mu)*isd, (p[5]-mu)*isd, (p[5]-mu)*isd };
            vf4 r67 = { (p[6]-mu)*isd, (p[6]-mu)*isd, (p[7]-mu)*isd, (p[7]-mu)*isd };
            __builtin_nontemporal_store(r01, op + 0);
            __builtin_nontemporal_store(r23, op + 1);
            __builtin_nontemporal_store(r45, op + 2);
            __builtin_nontemporal_store(r67, op + 3);
        }
        for (int j = G * V + tid; j < J; j += THREADS) {
            int s = 2 * j - mv; if (s < 0) s += L;
            int s1 = s + 1;     if (s1 >= L) s1 -= L;
            float pv = 0.5f * (xrow[s] + xrow[s1])
                     + 0.02f * (noise[2 * j] + noise[2 * j + 1]);
            float r = (pv - mu) * isd;
            orow[2 * j] = r; orow[2 * j + 1] = r;
        }
    } else {
        for (int j = tid; j < J; j += THREADS) {
            int s = 2 * j - mv; if (s < 0) s += L;
            int s1 = s + 1;     if (s1 >= L) s1 -= L;
            float pv = 0.5f * (xrow[s] + xrow[s1])
                     + 0.02f * (noise[2 * j] + noise[2 * j + 1]);
            float r = (pv - mu) * isd;
            orow[2 * j] = r; orow[2 * j + 1] = r;
        }
    }
}

extern "C" void kernel_launch(void* const* d_in, const int* in_sizes, int n_in,
                              void* d_out, int out_size, void* d_ws, size_t ws_size,
                              hipStream_t stream) {
    const float* x     = (const float*)d_in[0];
    const float* noise = (const float*)d_in[1];
    const int*   move  = (const int*)d_in[2];
    float*       out   = (float*)d_out;

    const int L = in_sizes[1];             // 100000
    const int B = in_sizes[0] / L;         // 512

    tbt_kernel<<<B, THREADS, 0, stream>>>(x, noise, move, out, L);
}

// Round 4
// 423.536 us; speedup vs baseline: 1.4088x; 1.4088x over previous
//
#include <hip/hip_runtime.h>

// TripleBatchTransform: roll(move) -> +noise*0.04 -> pairwise mean-pool
// (written twice) -> per-row standardize.
//
// p[j] = 0.5*(x[(2j-mv)%L] + x[(2j+1-mv)%L]) + 0.02*(noise[2j]+noise[2j+1])
// out[2j] = out[2j+1] = (p[j]-mu)*rsqrt(var), stats over pooled values
// (repeat-twice preserves mean/std).
//
// R4: revert R3's nontemporal stores (caused 2.75x HBM write amplification:
// 16B/lane partial-line writes bypassed L2 merging). Keep 8-pooled/thread
// wide loads (4x float4 x + 4x float4 noise = 64B/lane in flight).
// Blocks 1024 -> 256 threads (one row/block, 4 blocks/CU): finer phase
// barrier, cross-block phase overlap.

#define THREADS 256
#define NWAVES (THREADS / 64)
#define V 8  // pooled values per thread per group

typedef float vf4 __attribute__((ext_vector_type(4)));

__global__ __launch_bounds__(THREADS) void tbt_kernel(
    const float* __restrict__ x,
    const float* __restrict__ noise,
    const int* __restrict__ movep,
    float* __restrict__ out,
    int L)
{
    const int b   = blockIdx.x;
    const int tid = threadIdx.x;
    const int J   = L >> 1;        // pooled count per row
    const int G   = J / V;         // full groups of V pooled values

    int mv = movep[0];
    mv %= L;
    if (mv < 0) mv += L;

    const float* __restrict__ xrow = x + (size_t)b * (size_t)L;
    float* __restrict__ orow       = out + (size_t)b * (size_t)L;

    // 16B-aligned fast path needs (16g - mv) % 4 == 0 -> mv % 4 == 0.
    const bool fast = ((mv & 3) == 0) && ((L & 1) == 0);

    float sum = 0.f, sumsq = 0.f;
    float p[V];

    if (fast) {
        for (int g = tid; g < G; g += THREADS) {
            const int s0 = 2 * V * g - mv;
            if (s0 >= 0 && s0 + 2 * V <= L) {
                const vf4* xp = (const vf4*)(xrow + s0);
                const vf4* np = (const vf4*)(noise + 2 * V * g);
                vf4 xa = xp[0], xb = xp[1], xc = xp[2], xd = xp[3];
                vf4 na = np[0], nb = np[1], nc = np[2], nd = np[3];
                p[0] = 0.5f * (xa.x + xa.y) + 0.02f * (na.x + na.y);
                p[1] = 0.5f * (xa.z + xa.w) + 0.02f * (na.z + na.w);
                p[2] = 0.5f * (xb.x + xb.y) + 0.02f * (nb.x + nb.y);
                p[3] = 0.5f * (xb.z + xb.w) + 0.02f * (nb.z + nb.w);
                p[4] = 0.5f * (xc.x + xc.y) + 0.02f * (nc.x + nc.y);
                p[5] = 0.5f * (xc.z + xc.w) + 0.02f * (nc.z + nc.w);
                p[6] = 0.5f * (xd.x + xd.y) + 0.02f * (nd.x + nd.y);
                p[7] = 0.5f * (xd.z + xd.w) + 0.02f * (nd.z + nd.w);
            } else {
                #pragma unroll
                for (int k = 0; k < V; ++k) {
                    int j = V * g + k;
                    int s = 2 * j - mv; if (s < 0) s += L;
                    int s1 = s + 1;     if (s1 >= L) s1 -= L;
                    p[k] = 0.5f * (xrow[s] + xrow[s1])
                         + 0.02f * (noise[2 * j] + noise[2 * j + 1]);
                }
            }
            #pragma unroll
            for (int k = 0; k < V; ++k) { sum += p[k]; sumsq += p[k] * p[k]; }
        }
        // tail (J % V != 0)
        for (int j = G * V + tid; j < J; j += THREADS) {
            int s = 2 * j - mv; if (s < 0) s += L;
            int s1 = s + 1;     if (s1 >= L) s1 -= L;
            float pv = 0.5f * (xrow[s] + xrow[s1])
                     + 0.02f * (noise[2 * j] + noise[2 * j + 1]);
            sum += pv; sumsq += pv * pv;
        }
    } else {
        for (int j = tid; j < J; j += THREADS) {
            int s = 2 * j - mv; if (s < 0) s += L;
            int s1 = s + 1;     if (s1 >= L) s1 -= L;
            float pv = 0.5f * (xrow[s] + xrow[s1])
                     + 0.02f * (noise[2 * j] + noise[2 * j + 1]);
            sum += pv; sumsq += pv * pv;
        }
    }

    // wave reduction (64 lanes)
    #pragma unroll
    for (int off = 32; off > 0; off >>= 1) {
        sum   += __shfl_down(sum,   off, 64);
        sumsq += __shfl_down(sumsq, off, 64);
    }

    __shared__ float s_sum[NWAVES], s_sq[NWAVES];
    __shared__ float s_mu, s_isd;
    const int wave = tid >> 6;
    const int lane = tid & 63;
    if (lane == 0) { s_sum[wave] = sum; s_sq[wave] = sumsq; }
    __syncthreads();
    if (tid == 0) {
        float ts = 0.f, tq = 0.f;
        #pragma unroll
        for (int w = 0; w < NWAVES; ++w) { ts += s_sum[w]; tq += s_sq[w]; }
        float invJ = 1.0f / (float)J;
        float mu   = ts * invJ;
        float var  = tq * invJ - mu * mu;
        s_mu  = mu;
        s_isd = rsqrtf(fmaxf(var, 1e-30f));
    }
    __syncthreads();
    const float mu  = s_mu;
    const float isd = s_isd;

    // pass 2: recompute pooled (x re-read hits L3), write both slots.
    // Plain caching stores: L2 merges the 4x16B per-lane partials into
    // full lines (R3's NT stores defeated this -> 2.75x write traffic).
    if (fast) {
        for (int g = tid; g < G; g += THREADS) {
            const int s0 = 2 * V * g - mv;
            if (s0 >= 0 && s0 + 2 * V <= L) {
                const vf4* xp = (const vf4*)(xrow + s0);
                const vf4* np = (const vf4*)(noise + 2 * V * g);
                vf4 xa = xp[0], xb = xp[1], xc = xp[2], xd = xp[3];
                vf4 na = np[0], nb = np[1], nc = np[2], nd = np[3];
                p[0] = 0.5f * (xa.x + xa.y) + 0.02f * (na.x + na.y);
                p[1] = 0.5f * (xa.z + xa.w) + 0.02f * (na.z + na.w);
                p[2] = 0.5f * (xb.x + xb.y) + 0.02f * (nb.x + nb.y);
                p[3] = 0.5f * (xb.z + xb.w) + 0.02f * (nb.z + nb.w);
                p[4] = 0.5f * (xc.x + xc.y) + 0.02f * (nc.x + nc.y);
                p[5] = 0.5f * (xc.z + xc.w) + 0.02f * (nc.z + nc.w);
                p[6] = 0.5f * (xd.x + xd.y) + 0.02f * (nd.x + nd.y);
                p[7] = 0.5f * (xd.z + xd.w) + 0.02f * (nd.z + nd.w);
            } else {
                #pragma unroll
                for (int k = 0; k < V; ++k) {
                    int j = V * g + k;
                    int s = 2 * j - mv; if (s < 0) s += L;
                    int s1 = s + 1;     if (s1 >= L) s1 -= L;
                    p[k] = 0.5f * (xrow[s] + xrow[s1])
                         + 0.02f * (noise[2 * j] + noise[2 * j + 1]);
                }
            }
            vf4* op = (vf4*)(orow + 2 * V * g);
            vf4 r01 = { (p[0]-mu)*isd, (p[0]-mu)*isd, (p[1]-mu)*isd, (p[1]-mu)*isd };
            vf4 r23 = { (p[2]-mu)*isd, (p[2]-mu)*isd, (p[3]-mu)*isd, (p[3]-mu)*isd };
            vf4 r45 = { (p[4]-mu)*isd, (p[4]-mu)*isd, (p[5]-mu)*isd, (p[5]-mu)*isd };
            vf4 r67 = { (p[6]-mu)*isd, (p[6]-mu)*isd, (p[7]-mu)*isd, (p[7]-mu)*isd };
            op[0] = r01;
            op[1] = r23;
            op[2] = r45;
            op[3] = r67;
        }
        for (int j = G * V + tid; j < J; j += THREADS) {
            int s = 2 * j - mv; if (s < 0) s += L;
            int s1 = s + 1;     if (s1 >= L) s1 -= L;
            float pv = 0.5f * (xrow[s] + xrow[s1])
                     + 0.02f * (noise[2 * j] + noise[2 * j + 1]);
            float r = (pv - mu) * isd;
            orow[2 * j] = r; orow[2 * j + 1] = r;
        }
    } else {
        for (int j = tid; j < J; j += THREADS) {
            int s = 2 * j - mv; if (s < 0) s += L;
            int s1 = s + 1;     if (s1 >= L) s1 -= L;
            float pv = 0.5f * (xrow[s] + xrow[s1])
                     + 0.02f * (noise[2 * j] + noise[2 * j + 1]);
            float r = (pv - mu) * isd;
            orow[2 * j] = r; orow[2 * j + 1] = r;
        }
    }
}

extern "C" void kernel_launch(void* const* d_in, const int* in_sizes, int n_in,
                              void* d_out, int out_size, void* d_ws, size_t ws_size,
                              hipStream_t stream) {
    const float* x     = (const float*)d_in[0];
    const float* noise = (const float*)d_in[1];
    const int*   move  = (const int*)d_in[2];
    float*       out   = (float*)d_out;

    const int L = in_sizes[1];             // 100000
    const int B = in_sizes[0] / L;         // 512

    tbt_kernel<<<B, THREADS, 0, stream>>>(x, noise, move, out, L);
}